// Round 5
// baseline (254.547 us; speedup 1.0000x reference)
//
#include <hip/hip_runtime.h>

// QuantumLayer: B=8, L=2048, D=512, NQ=10, 4 layers, DIM=1024.
// R5 = exact R1 champion structure (best measured: 126us dispatch):
//   - 2 tokens per wave (ILP sweet spot at VGPR=64 / 8 waves per SIMD)
//   - ds_bpermute/DPP cross-lane (LDS pipe parallel to VALU; permlane-swap
//     variant measured WORSE: moved shuffles onto the saturated VALU pipe)
//   - separate tiny prep kernel (fusion measured worse: +40 VGPR -> 4-wave
//     occupancy bucket, 143us)
//   - rolled layer loop (I-cache bound)
// plus guarded micro-cuts:
//   - __launch_bounds__(256,8) pins the <=64-VGPR / 8-waves-per-SIMD bucket
//   - A=0.5+0.5*cos(f), C=0.5*sin(f) via __sincosf (drops half-angle mul and
//     c*c/c*s products; shortens dependent chain before build_product)
//
// Measured landscape (dispatch us / VGPR / occupancy%):
//   1tok 158/48/51; 2tok 126/64/36 <-- best; 2tok+permlane 142 (VALU +27%);
//   4tok 140/104/20; 2tok+LDSfusion 143/104/21.
// VALU instr/wave ~6.5k vs ~6k complex-SU(2) floor -> instruction count is
// near-minimal; the lever is ILP x occupancy, maximized at this config.
//
// Statevector packed as half2 per token: amplitude index i (10 bits):
//   lane = i>>4 (bits 9..4), reg r = i&15; r = 2*j + e (j = VGPR idx, e = half)
// qubit q at bit 9-q: q0..q5 -> lane bits 5..0; q6 -> j bit2, q7 -> j bit1,
// q8 -> j bit0, q9 -> element(half).
//
// Per layer/qubit RX(f)->phase(f)->RY(w0)->RZ(w1) fuse into one SU(2) gate
// (ar,ai,br,bi) = Q0 + A*Q1 + C*Q2, A=c^2, C=c*s. Q* weight-only, stored in
// d_ws BOTH as f32 (layer-0 product-state build) and packed f16 (layers 1..3
// coef math in v_pk_fma_f16). Final CNOT ring absorbed into measurement signs.
#define NQ 10
#define DQ 512
#define QL 4
#define NTOK (8 * 2048)
#define QOFF (NQ * DQ)          // float offset of f32 Q tables inside ws
#define QHOFF (QOFF + 480)      // float offset of f16 Q tables inside ws

typedef float v2f __attribute__((ext_vector_type(2)));
typedef float v4f __attribute__((ext_vector_type(4)));
typedef _Float16 h2 __attribute__((ext_vector_type(2)));

// ---- cross-lane helpers (HW-proven R0/R1) ----------------------------------
__device__ __forceinline__ int bperm(int addr, int v) {
    return __builtin_amdgcn_ds_bpermute(addr, v);
}
__device__ __forceinline__ float bpermf(int addr, float v) {
    return __builtin_bit_cast(float, bperm(addr, __builtin_bit_cast(int, v)));
}
__device__ __forceinline__ h2 bpermh(int addr, h2 v) {
    return __builtin_bit_cast(h2, bperm(addr, __builtin_bit_cast(int, v)));
}
template <int CTRL>
__device__ __forceinline__ int dppi(int i) {
    return __builtin_amdgcn_update_dpp(i, i, CTRL, 0xF, 0xF, false);
}
template <int M>   // M in {1,2,8}
__device__ __forceinline__ float dppxf(float v) {
    int i = __builtin_bit_cast(int, v);
    if constexpr (M == 1)      i = dppi<0xB1>(i);   // quad_perm [1,0,3,2]
    else if constexpr (M == 2) i = dppi<0x4E>(i);   // quad_perm [2,3,0,1]
    else                       i = dppi<0x128>(i);  // row_ror:8 == xor 8
    return __builtin_bit_cast(float, i);
}
template <int M>   // M in {1,2,8}
__device__ __forceinline__ h2 dppxh(h2 v) {
    int i = __builtin_bit_cast(int, v);
    if constexpr (M == 1)      i = dppi<0xB1>(i);
    else if constexpr (M == 2) i = dppi<0x4E>(i);
    else                       i = dppi<0x128>(i);
    return __builtin_bit_cast(h2, i);
}

// f32 butterfly broadcast-reduce over 64 lanes, N independent values
template <int N>
__device__ __forceinline__ void reduceNf(float* z, int a32, int a16, int a4) {
#pragma unroll
    for (int q = 0; q < N; ++q) {
        z[q] += bpermf(a32, z[q]);
        z[q] += bpermf(a16, z[q]);
        z[q] += dppxf<8>(z[q]);
        z[q] += bpermf(a4, z[q]);
        z[q] += dppxf<2>(z[q]);
        z[q] += dppxf<1>(z[q]);
    }
}

__device__ __forceinline__ h2 pk2(float a, float b) {
    return __builtin_bit_cast(h2, __builtin_amdgcn_cvt_pkrtz(a, b));
}
__device__ __forceinline__ h2 h2swap(h2 v) {
    return __builtin_shufflevector(v, v, 1, 0);
}
__device__ __forceinline__ h2 splat_lo(h2 v) {
    return __builtin_shufflevector(v, v, 0, 0);
}
__device__ __forceinline__ h2 splat_hi(h2 v) {
    return __builtin_shufflevector(v, v, 1, 1);
}

// f32 coef for layer-0 build: Q0 + A*Q1 + C*Q2
__device__ __forceinline__ v4f coef(const v4f* Q, float A, float C) {
    return Q[0] + A * Q[1] + C * Q[2];
}
// f16 coef for layers 1..3, both tokens: per gate 6 h2 at Qg6 -> (arai, brbi)
__device__ __forceinline__ void coefh2(const h2* Qg6, const h2 AC[2][NQ], int q,
                                       h2* arai, h2* brbi) {
    const h2 q0 = Qg6[0], q1 = Qg6[1], q2 = Qg6[2];
    const h2 q3 = Qg6[3], q4 = Qg6[4], q5 = Qg6[5];
#pragma unroll
    for (int tt = 0; tt < 2; ++tt) {
        h2 A2 = splat_lo(AC[tt][q]), C2 = splat_hi(AC[tt][q]);
        arai[tt] = q0 + A2 * q2 + C2 * q4;
        brbi[tt] = q1 + A2 * q3 + C2 * q5;
    }
}

// ---- SU(2) gate application on f16-packed state, 2 tokens interleaved ------
__device__ __forceinline__ void gate_lane_hp2(h2 (&sr)[2][8], h2 (&si)[2][8],
                                              const h2* arai, const h2* brbi,
                                              bool bit, int addr) {
    h2 ar[2], br[2], bi[2], Ai[2], Br[2];
#pragma unroll
    for (int tt = 0; tt < 2; ++tt) {
        ar[tt] = splat_lo(arai[tt]);
        h2 ai = splat_hi(arai[tt]);
        br[tt] = splat_lo(brbi[tt]);
        bi[tt] = splat_hi(brbi[tt]);
        Ai[tt] = bit ? -ai : ai;
        Br[tt] = bit ? br[tt] : -br[tt];
    }
#pragma unroll
    for (int j = 0; j < 8; ++j)
#pragma unroll
        for (int tt = 0; tt < 2; ++tt) {
            h2 wr = bpermh(addr, sr[tt][j]), wi = bpermh(addr, si[tt][j]);
            h2 nr = ar[tt] * sr[tt][j] - Ai[tt] * si[tt][j] + Br[tt] * wr - bi[tt] * wi;
            h2 ni = ar[tt] * si[tt][j] + Ai[tt] * sr[tt][j] + Br[tt] * wi + bi[tt] * wr;
            sr[tt][j] = nr; si[tt][j] = ni;
        }
}
template <int M>
__device__ __forceinline__ void gate_lane_hd2(h2 (&sr)[2][8], h2 (&si)[2][8],
                                              const h2* arai, const h2* brbi,
                                              bool bit) {
    h2 ar[2], br[2], bi[2], Ai[2], Br[2];
#pragma unroll
    for (int tt = 0; tt < 2; ++tt) {
        ar[tt] = splat_lo(arai[tt]);
        h2 ai = splat_hi(arai[tt]);
        br[tt] = splat_lo(brbi[tt]);
        bi[tt] = splat_hi(brbi[tt]);
        Ai[tt] = bit ? -ai : ai;
        Br[tt] = bit ? br[tt] : -br[tt];
    }
#pragma unroll
    for (int j = 0; j < 8; ++j)
#pragma unroll
        for (int tt = 0; tt < 2; ++tt) {
            h2 wr = dppxh<M>(sr[tt][j]), wi = dppxh<M>(si[tt][j]);
            h2 nr = ar[tt] * sr[tt][j] - Ai[tt] * si[tt][j] + Br[tt] * wr - bi[tt] * wi;
            h2 ni = ar[tt] * si[tt][j] + Ai[tt] * sr[tt][j] + Br[tt] * wi + bi[tt] * wr;
            sr[tt][j] = nr; si[tt][j] = ni;
        }
}
template <int BJ>
__device__ __forceinline__ void gate_reg_h2(h2 (&sr)[2][8], h2 (&si)[2][8],
                                            const h2* arai, const h2* brbi) {
#pragma unroll
    for (int tt = 0; tt < 2; ++tt) {
        const h2 ar = splat_lo(arai[tt]), ai = splat_hi(arai[tt]);
        const h2 br = splat_lo(brbi[tt]), bi = splat_hi(brbi[tt]);
#pragma unroll
        for (int j = 0; j < 8; ++j) if (!(j & BJ)) {
            const int j1 = j | BJ;
            h2 x0r = sr[tt][j], x0i = si[tt][j];
            h2 x1r = sr[tt][j1], x1i = si[tt][j1];
            sr[tt][j]  = ar * x0r - ai * x0i - br * x1r - bi * x1i;
            si[tt][j]  = ar * x0i + ai * x0r - br * x1i + bi * x1r;
            sr[tt][j1] = br * x0r - bi * x0i + ar * x1r + ai * x1i;
            si[tt][j1] = br * x0i + bi * x0r + ar * x1i - ai * x1r;
        }
    }
}
__device__ __forceinline__ void gate_elem_h2(h2 (&sr)[2][8], h2 (&si)[2][8],
                                             const h2* arai, const h2* brbi) {
#pragma unroll
    for (int tt = 0; tt < 2; ++tt) {
        const h2 ar = splat_lo(arai[tt]), bi = splat_hi(brbi[tt]);
        // aiV = (ai, -ai): negate hi half; brV = (-br, br): negate lo half
        const h2 aiV = __builtin_bit_cast(h2,
            __builtin_bit_cast(int, splat_hi(arai[tt])) ^ (int)0x80000000);
        const h2 brV = __builtin_bit_cast(h2,
            __builtin_bit_cast(int, splat_lo(brbi[tt])) ^ 0x00008000);
#pragma unroll
        for (int j = 0; j < 8; ++j) {
            h2 swr = h2swap(sr[tt][j]), swi = h2swap(si[tt][j]);
            h2 nr = ar * sr[tt][j] - aiV * si[tt][j] + brV * swr - bi * swi;
            h2 ni = ar * si[tt][j] + aiV * sr[tt][j] + brV * swi + bi * swr;
            sr[tt][j] = nr; si[tt][j] = ni;
        }
    }
}

// CNOT q=6,7,8 composed register permutation
__device__ __forceinline__ void perm678_h(h2* a) {
    h2 o2 = a[2], o4 = a[4], o7 = a[7];
    a[1] = h2swap(a[1]);
    a[2] = a[3]; a[3] = h2swap(o2);
    a[4] = a[6]; a[6] = a[5]; a[5] = h2swap(o7); a[7] = h2swap(o4);
}

// ring CNOTs q -> q+1 (mod 10), 2 tokens interleaved
__device__ __forceinline__ void cnot_ring2(h2 (&sr)[2][8], h2 (&si)[2][8],
                                           int lane, int apm, int a32) {
#pragma unroll
    for (int j = 0; j < 8; ++j)
#pragma unroll
        for (int tt = 0; tt < 2; ++tt) {
            sr[tt][j] = bpermh(apm, sr[tt][j]);
            si[tt][j] = bpermh(apm, si[tt][j]);
        }
    {
        const bool ctrl = (lane & 1);
#pragma unroll
        for (int tt = 0; tt < 2; ++tt)
#pragma unroll
            for (int j = 0; j < 4; ++j) {
                h2 t0 = sr[tt][j], t1 = sr[tt][j + 4];
                sr[tt][j] = ctrl ? t1 : t0; sr[tt][j + 4] = ctrl ? t0 : t1;
                t0 = si[tt][j]; t1 = si[tt][j + 4];
                si[tt][j] = ctrl ? t1 : t0; si[tt][j + 4] = ctrl ? t0 : t1;
            }
    }
#pragma unroll
    for (int tt = 0; tt < 2; ++tt) {
        perm678_h(sr[tt]);
        perm678_h(si[tt]);
    }
#pragma unroll
    for (int j = 0; j < 8; ++j)
#pragma unroll
        for (int tt = 0; tt < 2; ++tt) {
            h2 w = bpermh(a32, sr[tt][j]); sr[tt][j] = (h2){sr[tt][j].x, w.y};
            w = bpermh(a32, si[tt][j]);    si[tt][j] = (h2){si[tt][j].x, w.y};
        }
}

// layer-0 product-state build (fp32), one token
__device__ __forceinline__ void build_product(h2* sr, h2* si, const v4f* Q0,
                                              const float* Aq, const float* Cq,
                                              int lane) {
    v4f f0 = coef(Q0 + 0, Aq[0], Cq[0]);
    bool b0 = (lane & 32);
    float Lr = b0 ? f0.z : f0.x, Li = b0 ? f0.w : f0.y;
#pragma unroll
    for (int q = 1; q < 6; ++q) {
        v4f f = coef(Q0 + 3 * q, Aq[q], Cq[q]);
        bool b = lane & (1 << (5 - q));
        float fr = b ? f.z : f.x, fi = b ? f.w : f.y;
        float nr = Lr * fr - Li * fi, ni = Lr * fi + Li * fr;
        Lr = nr; Li = ni;
    }
    float Pr[8], Pi[8];
    {   // q6 -> j bit2
        v4f f6 = coef(Q0 + 18, Aq[6], Cq[6]);
        Pr[0] = Lr * f6.x - Li * f6.y; Pi[0] = Lr * f6.y + Li * f6.x;
        Pr[4] = Lr * f6.z - Li * f6.w; Pi[4] = Lr * f6.w + Li * f6.z;
    }
    {   // q7 -> j bit1
        v4f f7 = coef(Q0 + 21, Aq[7], Cq[7]);
#pragma unroll
        for (int jj = 0; jj < 8; jj += 4) {
            float tr1 = Pr[jj] * f7.z - Pi[jj] * f7.w;
            float ti1 = Pr[jj] * f7.w + Pi[jj] * f7.z;
            float tr0 = Pr[jj] * f7.x - Pi[jj] * f7.y;
            float ti0 = Pr[jj] * f7.y + Pi[jj] * f7.x;
            Pr[jj] = tr0; Pi[jj] = ti0; Pr[jj + 2] = tr1; Pi[jj + 2] = ti1;
        }
    }
    {   // q8 -> j bit0
        v4f f8 = coef(Q0 + 24, Aq[8], Cq[8]);
#pragma unroll
        for (int jj = 0; jj < 8; jj += 2) {
            float tr1 = Pr[jj] * f8.z - Pi[jj] * f8.w;
            float ti1 = Pr[jj] * f8.w + Pi[jj] * f8.z;
            float tr0 = Pr[jj] * f8.x - Pi[jj] * f8.y;
            float ti0 = Pr[jj] * f8.y + Pi[jj] * f8.x;
            Pr[jj] = tr0; Pi[jj] = ti0; Pr[jj + 1] = tr1; Pi[jj + 1] = ti1;
        }
    }
    {   // q9 -> element
        v4f f9 = coef(Q0 + 27, Aq[9], Cq[9]);
#pragma unroll
        for (int j = 0; j < 8; ++j) {
            float e0r = Pr[j] * f9.x - Pi[j] * f9.y;
            float e0i = Pr[j] * f9.y + Pi[j] * f9.x;
            float e1r = Pr[j] * f9.z - Pi[j] * f9.w;
            float e1i = Pr[j] * f9.w + Pi[j] * f9.z;
            sr[j] = pk2(e0r, e1r);
            si[j] = pk2(e0i, e1i);
        }
    }
}

// ---- prep kernel: transposed out_W + Q tables (f32 and packed f16) ---------
__global__ __launch_bounds__(512) void prep_kernel(
    const float* __restrict__ weights, const float* __restrict__ out_W,
    float* __restrict__ ws)
{
    const int t = threadIdx.x;   // 512 threads
#pragma unroll
    for (int q = 0; q < NQ; ++q)
        ws[q * DQ + t] = out_W[t * NQ + q];
    if (t < QL * NQ) {
        float w0 = weights[t * 2], w1 = weights[t * 2 + 1];
        float cy = __cosf(0.5f * w0), sy = __sinf(0.5f * w0);
        float cz = __cosf(0.5f * w1), sz = __sinf(0.5f * w1);
        float d = cy - sy, e = cy + sy;
        v4f q0 = (v4f){-cz * sy,  sz * sy,  cz * cy,  sz * cy};
        v4f q1 = (v4f){ cz * e,  -sz * e,  -cz * d,  -sz * d};
        v4f q2 = (v4f){-sz * d,  -cz * d,   sz * e,  -cz * e};
        v4f* Q = (v4f*)(ws + QOFF);
        Q[t * 3 + 0] = q0; Q[t * 3 + 1] = q1; Q[t * 3 + 2] = q2;
        h2* Qh = (h2*)(ws + QHOFF);
        Qh[t * 6 + 0] = pk2(q0.x, q0.y); Qh[t * 6 + 1] = pk2(q0.z, q0.w);
        Qh[t * 6 + 2] = pk2(q1.x, q1.y); Qh[t * 6 + 3] = pk2(q1.z, q1.w);
        Qh[t * 6 + 4] = pk2(q2.x, q2.y); Qh[t * 6 + 5] = pk2(q2.z, q2.w);
    }
}

__global__ __launch_bounds__(256, 8) void quantum_kernel(
    const float* __restrict__ x, const float* __restrict__ in_W,
    const float* __restrict__ in_b, const float* __restrict__ gamma,
    const float* __restrict__ beta, const float* __restrict__ ws,
    const float* __restrict__ out_b, float* __restrict__ out)
{
    const int t = threadIdx.x;
    const int lane = t & 63;
    const int tok0 = (blockIdx.x * 4 + (t >> 6)) * 2;   // 2 tokens per wave
    const v4f* Qg = (const v4f*)(ws + QOFF);    // f32 (layer 0)
    const h2*  Qh = (const h2*)(ws + QHOFF);    // f16 (layers 1..3)

    // hoisted bpermute byte addresses
    const int a32 = (lane ^ 32) << 2;
    const int a16 = (lane ^ 16) << 2;
    const int a4  = (lane ^ 4)  << 2;
    int srcl = lane;
#pragma unroll
    for (int q = 4; q >= 0; --q) {
        const int bc = 5 - q, bt = bc - 1;
        srcl ^= ((srcl >> bc) & 1) << bt;
    }
    const int apm = srcl << 2;

    // ---------------- stage 1: h = tanh(x @ in_W^T + in_b), then LN ----------
    const v4f* xr0 = (const v4f*)(x + (size_t)tok0 * DQ);
    const v4f* xr1 = (const v4f*)(x + (size_t)(tok0 + 1) * DQ);
    const v4f* inW4 = (const v4f*)in_W;
    const v4f xk00 = xr0[lane], xk01 = xr0[lane + 64];
    const v4f xk10 = xr1[lane], xk11 = xr1[lane + 64];
    float h[2][NQ];
#pragma unroll
    for (int q = 0; q < NQ; ++q) {
        v4f w0 = inW4[q * (DQ / 4) + lane];
        v4f w1 = inW4[q * (DQ / 4) + lane + 64];
        v4f a0 = xk00 * w0 + xk01 * w1;
        v4f a1 = xk10 * w0 + xk11 * w1;
        h[0][q] = (a0.x + a0.y) + (a0.z + a0.w);
        h[1][q] = (a1.x + a1.y) + (a1.z + a1.w);
    }
    reduceNf<2 * NQ>(&h[0][0], a32, a16, a4);

    h2 AC[2][NQ];           // (A, C) packed per token/qubit
    h2 sr[2][8], si[2][8];  // statevectors
#pragma unroll
    for (int tt = 0; tt < 2; ++tt) {
        float mu = 0.f;
#pragma unroll
        for (int q = 0; q < NQ; ++q) {
            float e = __expf(2.f * (h[tt][q] + in_b[q]));
            h[tt][q] = (e - 1.f) * __builtin_amdgcn_rcpf(e + 1.f);
            mu += h[tt][q];
        }
        mu *= 0.1f;
        float var = 0.f;
#pragma unroll
        for (int q = 0; q < NQ; ++q) { float d0 = h[tt][q] - mu; var += d0 * d0; }
        var *= 0.1f;
        const float rstd = rsqrtf(var + 1e-5f);

        float Aq[NQ], Cq[NQ];
#pragma unroll
        for (int q = 0; q < NQ; ++q) {
            float f = (h[tt][q] - mu) * rstd * gamma[q] + beta[q];
            // A = cos^2(f/2) = 0.5 + 0.5*cos(f); C = cos(f/2)sin(f/2) = 0.5*sin(f)
            float sf, cf;
            __sincosf(f, &sf, &cf);
            Aq[q] = fmaf(0.5f, cf, 0.5f);
            Cq[q] = 0.5f * sf;
            AC[tt][q] = pk2(Aq[q], Cq[q]);
        }
        // ---------------- layer 0: product state built directly (fp32) ------
        build_product(sr[tt], si[tt], Qg, Aq, Cq, lane);
    }
    cnot_ring2(sr, si, lane, apm, a32);

    // ---------------- layers 1..3 (final ring absorbed into measurement) -----
    // rolled: keeps I-cache footprint ~1/3 of full unroll
#pragma unroll 1
    for (int l = 1; l < QL; ++l) {
        const h2* Ql = Qh + l * NQ * 6;
        h2 arai[2], brbi[2];
        coefh2(Ql + 0 * 6, AC, 0, arai, brbi); gate_lane_hp2(sr, si, arai, brbi, lane & 32, a32);
        coefh2(Ql + 2 * 6, AC, 2, arai, brbi); gate_lane_hd2<8>(sr, si, arai, brbi, lane & 8);
        coefh2(Ql + 1 * 6, AC, 1, arai, brbi); gate_lane_hp2(sr, si, arai, brbi, lane & 16, a16);
        coefh2(Ql + 4 * 6, AC, 4, arai, brbi); gate_lane_hd2<2>(sr, si, arai, brbi, lane & 2);
        coefh2(Ql + 3 * 6, AC, 3, arai, brbi); gate_lane_hp2(sr, si, arai, brbi, lane & 4, a4);
        coefh2(Ql + 5 * 6, AC, 5, arai, brbi); gate_lane_hd2<1>(sr, si, arai, brbi, lane & 1);
        coefh2(Ql + 6 * 6, AC, 6, arai, brbi); gate_reg_h2<4>(sr, si, arai, brbi);
        coefh2(Ql + 7 * 6, AC, 7, arai, brbi); gate_reg_h2<2>(sr, si, arai, brbi);
        coefh2(Ql + 8 * 6, AC, 8, arai, brbi); gate_reg_h2<1>(sr, si, arai, brbi);
        coefh2(Ql + 9 * 6, AC, 9, arai, brbi); gate_elem_h2(sr, si, arai, brbi);
        if (l < QL - 1) cnot_ring2(sr, si, lane, apm, a32);
    }

    // ---------------- measurement (packed f16, ring-relabeled signs) ---------
    const bool P1 = __popc(lane & 0x30) & 1;
    const bool P2 = __popc(lane & 0x38) & 1;
    const bool P3 = __popc(lane & 0x3C) & 1;
    const bool P4 = __popc(lane & 0x3E) & 1;
    const bool P5 = __popc(lane & 0x3F) & 1;
    const bool PX = __popc(lane & 0x1F) & 1;   // qubit0: P9 ^ Q0
    h2 zp[10];  // [tt*5 + i]
#pragma unroll
    for (int tt = 0; tt < 2; ++tt) {
        h2 aP = (h2){0, 0}, a6 = (h2){0, 0}, a7 = (h2){0, 0}, aT = (h2){0, 0};
#pragma unroll
        for (int j = 0; j < 8; ++j) {
            h2 p = sr[tt][j] * sr[tt][j] + si[tt][j] * si[tt][j];
            aP += p;
            if (j & 4) a6 -= p; else a6 += p;                        // j2
            if (((j >> 2) ^ (j >> 1)) & 1) a7 -= p; else a7 += p;    // j2^j1
            if (((j >> 2) ^ (j >> 1) ^ j) & 1) aT -= p; else aT += p;// j2^j1^j0
        }
        const float A0 = (float)aP.x + (float)aP.y;
        const float B6 = (float)a6.x + (float)a6.y;
        const float B7 = (float)a7.x + (float)a7.y;
        const float B8 = (float)aT.x + (float)aT.y;
        const float B9 = (float)aT.x - (float)aT.y;
        float z[NQ];
        z[0] = PX ? -B9 : B9;
        z[1] = P1 ? -A0 : A0;
        z[2] = P2 ? -A0 : A0;
        z[3] = P3 ? -A0 : A0;
        z[4] = P4 ? -A0 : A0;
        z[5] = P5 ? -A0 : A0;
        z[6] = P5 ? -B6 : B6;
        z[7] = P5 ? -B7 : B7;
        z[8] = P5 ? -B8 : B8;
        z[9] = P5 ? -B9 : B9;
#pragma unroll
        for (int i = 0; i < 5; ++i) zp[tt * 5 + i] = pk2(z[2 * i], z[2 * i + 1]);
    }

    // packed f16 butterfly broadcast-reduce of z (10 h2 regs, 6 steps)
#pragma unroll
    for (int i = 0; i < 10; ++i) {
        zp[i] += bpermh(a32, zp[i]);
        zp[i] += bpermh(a16, zp[i]);
        zp[i] += dppxh<8>(zp[i]);
        zp[i] += bpermh(a4, zp[i]);
        zp[i] += dppxh<2>(zp[i]);
        zp[i] += dppxh<1>(zp[i]);
    }
    float zf[2][NQ];
#pragma unroll
    for (int tt = 0; tt < 2; ++tt)
#pragma unroll
        for (int i = 0; i < 5; ++i) {
            zf[tt][2 * i]     = (float)zp[tt * 5 + i].x;
            zf[tt][2 * i + 1] = (float)zp[tt * 5 + i].y;
        }

    // ---------------- epilogue: out = x + z @ out_W^T + out_b ----------------
    v4f* or0 = (v4f*)(out + (size_t)tok0 * DQ);
    v4f* or1 = (v4f*)(out + (size_t)(tok0 + 1) * DQ);
    const v4f* ob4 = (const v4f*)out_b;
    const v4f* oWt4 = (const v4f*)ws;   // transposed out_W [q][d]
#pragma unroll
    for (int k = 0; k < 2; ++k) {
        const int d4 = lane + 64 * k;
        const v4f b = ob4[d4];
        v4f acc0 = xr0[d4] + b;
        v4f acc1 = xr1[d4] + b;
#pragma unroll
        for (int q = 0; q < NQ; ++q) {
            v4f w = oWt4[q * (DQ / 4) + d4];
            acc0 = zf[0][q] * w + acc0;
            acc1 = zf[1][q] * w + acc1;
        }
        or0[d4] = acc0;
        or1[d4] = acc1;
    }
}

extern "C" void kernel_launch(void* const* d_in, const int* in_sizes, int n_in,
                              void* d_out, int out_size, void* d_ws, size_t ws_size,
                              hipStream_t stream) {
    const float* x       = (const float*)d_in[0];
    const float* in_W    = (const float*)d_in[1];
    const float* in_b    = (const float*)d_in[2];
    const float* gamma   = (const float*)d_in[3];
    const float* beta    = (const float*)d_in[4];
    const float* weights = (const float*)d_in[5];
    const float* out_W   = (const float*)d_in[6];
    const float* out_b   = (const float*)d_in[7];
    float* out = (float*)d_out;
    float* ws = (float*)d_ws;

    hipLaunchKernelGGL(prep_kernel, dim3(1), dim3(512), 0, stream,
                       weights, out_W, ws);
    hipLaunchKernelGGL(quantum_kernel, dim3(NTOK / 8), dim3(256), 0, stream,
                       x, in_W, in_b, gamma, beta, ws, out_b, out);
}

// Round 6
// 193.920 us; speedup vs baseline: 1.3126x; 1.3126x over previous
//
#include <hip/hip_runtime.h>

// QuantumLayer: B=8, L=2048, D=512, NQ=10, 4 layers, DIM=1024.
// R6 = VERBATIM R1 champion (best measured: 126us dispatch, 192.7us scored).
// Five rounds of deviations all measured worse:
//   permlane-swap shuffles  -> 142us (moved shuffles onto saturated VALU pipe)
//   4 tokens/wave           -> 140us (VGPR 104, occupancy cliff at >64)
//   LDS-fused prep          -> 143us (same cliff)
//   launch_bounds(256,8)+sincosf -> 185-205us (compiler spilled state to
//       scratch: VGPR 32, WRITE_SIZE 32MB->300MB. NEVER pin min-waves on a
//       register-tight kernel; never use pointer-output math intrinsics.)
// Landscape: instruction count ~10% above complex-SU(2) floor; ILP x
// occupancy maximized at the VGPR-64 / 8-waves-per-SIMD boundary; VALU/LDS
// pipe mix balanced. This config is the measured bowl bottom.
//
// TWO tokens per wave (ILP: the serial gate chain is latency-bound; a second
// independent token interleaved at the j-loop level fills stall cycles).
// Statevector packed as half2 per token: amplitude index i (10 bits):
//   lane = i>>4 (bits 9..4), reg r = i&15; r = 2*j + e (j = VGPR idx, e = half)
// qubit q at bit 9-q: q0..q5 -> lane bits 5..0; q6 -> j bit2, q7 -> j bit1,
// q8 -> j bit0, q9 -> element(half).
//
// Per layer/qubit RX(f)->phase(f)->RY(w0)->RZ(w1) fuse into one SU(2) gate
// (ar,ai,br,bi) = Q0 + A*Q1 + C*Q2, A=c^2, C=c*s. Q* weight-only, stored in
// d_ws BOTH as f32 (layer-0 product-state build) and packed f16 (layers 1..3
// coef math in v_pk_fma_f16). Final CNOT ring absorbed into measurement signs.
// Layer loop rolled (#pragma unroll 1) to keep I-cache footprint bounded.
#define NQ 10
#define DQ 512
#define QL 4
#define NTOK (8 * 2048)
#define QOFF (NQ * DQ)          // float offset of f32 Q tables inside ws
#define QHOFF (QOFF + 480)      // float offset of f16 Q tables inside ws

typedef float v2f __attribute__((ext_vector_type(2)));
typedef float v4f __attribute__((ext_vector_type(4)));
typedef _Float16 h2 __attribute__((ext_vector_type(2)));

// ---- cross-lane helpers (HW-proven) ----------------------------------------
__device__ __forceinline__ int bperm(int addr, int v) {
    return __builtin_amdgcn_ds_bpermute(addr, v);
}
__device__ __forceinline__ float bpermf(int addr, float v) {
    return __builtin_bit_cast(float, bperm(addr, __builtin_bit_cast(int, v)));
}
__device__ __forceinline__ h2 bpermh(int addr, h2 v) {
    return __builtin_bit_cast(h2, bperm(addr, __builtin_bit_cast(int, v)));
}
template <int CTRL>
__device__ __forceinline__ int dppi(int i) {
    return __builtin_amdgcn_update_dpp(i, i, CTRL, 0xF, 0xF, false);
}
template <int M>   // M in {1,2,8}
__device__ __forceinline__ float dppxf(float v) {
    int i = __builtin_bit_cast(int, v);
    if constexpr (M == 1)      i = dppi<0xB1>(i);   // quad_perm [1,0,3,2]
    else if constexpr (M == 2) i = dppi<0x4E>(i);   // quad_perm [2,3,0,1]
    else                       i = dppi<0x128>(i);  // row_ror:8 == xor 8
    return __builtin_bit_cast(float, i);
}
template <int M>   // M in {1,2,8}
__device__ __forceinline__ h2 dppxh(h2 v) {
    int i = __builtin_bit_cast(int, v);
    if constexpr (M == 1)      i = dppi<0xB1>(i);
    else if constexpr (M == 2) i = dppi<0x4E>(i);
    else                       i = dppi<0x128>(i);
    return __builtin_bit_cast(h2, i);
}

// f32 butterfly broadcast-reduce over 64 lanes, N independent values
template <int N>
__device__ __forceinline__ void reduceNf(float* z, int a32, int a16, int a4) {
#pragma unroll
    for (int q = 0; q < N; ++q) {
        z[q] += bpermf(a32, z[q]);
        z[q] += bpermf(a16, z[q]);
        z[q] += dppxf<8>(z[q]);
        z[q] += bpermf(a4, z[q]);
        z[q] += dppxf<2>(z[q]);
        z[q] += dppxf<1>(z[q]);
    }
}

__device__ __forceinline__ h2 pk2(float a, float b) {
    return __builtin_bit_cast(h2, __builtin_amdgcn_cvt_pkrtz(a, b));
}
__device__ __forceinline__ h2 h2swap(h2 v) {
    return __builtin_shufflevector(v, v, 1, 0);
}
__device__ __forceinline__ h2 splat_lo(h2 v) {
    return __builtin_shufflevector(v, v, 0, 0);
}
__device__ __forceinline__ h2 splat_hi(h2 v) {
    return __builtin_shufflevector(v, v, 1, 1);
}

// f32 coef for layer-0 build: Q0 + A*Q1 + C*Q2
__device__ __forceinline__ v4f coef(const v4f* Q, float A, float C) {
    return Q[0] + A * Q[1] + C * Q[2];
}
// f16 coef for layers 1..3, both tokens: per gate 6 h2 at Qg6 -> (arai, brbi)
__device__ __forceinline__ void coefh2(const h2* Qg6, const h2 AC[2][NQ], int q,
                                       h2* arai, h2* brbi) {
    const h2 q0 = Qg6[0], q1 = Qg6[1], q2 = Qg6[2];
    const h2 q3 = Qg6[3], q4 = Qg6[4], q5 = Qg6[5];
#pragma unroll
    for (int tt = 0; tt < 2; ++tt) {
        h2 A2 = splat_lo(AC[tt][q]), C2 = splat_hi(AC[tt][q]);
        arai[tt] = q0 + A2 * q2 + C2 * q4;
        brbi[tt] = q1 + A2 * q3 + C2 * q5;
    }
}

// ---- SU(2) gate application on f16-packed state, 2 tokens interleaved ------
__device__ __forceinline__ void gate_lane_hp2(h2 (&sr)[2][8], h2 (&si)[2][8],
                                              const h2* arai, const h2* brbi,
                                              bool bit, int addr) {
    h2 ar[2], br[2], bi[2], Ai[2], Br[2];
#pragma unroll
    for (int tt = 0; tt < 2; ++tt) {
        ar[tt] = splat_lo(arai[tt]);
        h2 ai = splat_hi(arai[tt]);
        br[tt] = splat_lo(brbi[tt]);
        bi[tt] = splat_hi(brbi[tt]);
        Ai[tt] = bit ? -ai : ai;
        Br[tt] = bit ? br[tt] : -br[tt];
    }
#pragma unroll
    for (int j = 0; j < 8; ++j)
#pragma unroll
        for (int tt = 0; tt < 2; ++tt) {
            h2 wr = bpermh(addr, sr[tt][j]), wi = bpermh(addr, si[tt][j]);
            h2 nr = ar[tt] * sr[tt][j] - Ai[tt] * si[tt][j] + Br[tt] * wr - bi[tt] * wi;
            h2 ni = ar[tt] * si[tt][j] + Ai[tt] * sr[tt][j] + Br[tt] * wi + bi[tt] * wr;
            sr[tt][j] = nr; si[tt][j] = ni;
        }
}
template <int M>
__device__ __forceinline__ void gate_lane_hd2(h2 (&sr)[2][8], h2 (&si)[2][8],
                                              const h2* arai, const h2* brbi,
                                              bool bit) {
    h2 ar[2], br[2], bi[2], Ai[2], Br[2];
#pragma unroll
    for (int tt = 0; tt < 2; ++tt) {
        ar[tt] = splat_lo(arai[tt]);
        h2 ai = splat_hi(arai[tt]);
        br[tt] = splat_lo(brbi[tt]);
        bi[tt] = splat_hi(brbi[tt]);
        Ai[tt] = bit ? -ai : ai;
        Br[tt] = bit ? br[tt] : -br[tt];
    }
#pragma unroll
    for (int j = 0; j < 8; ++j)
#pragma unroll
        for (int tt = 0; tt < 2; ++tt) {
            h2 wr = dppxh<M>(sr[tt][j]), wi = dppxh<M>(si[tt][j]);
            h2 nr = ar[tt] * sr[tt][j] - Ai[tt] * si[tt][j] + Br[tt] * wr - bi[tt] * wi;
            h2 ni = ar[tt] * si[tt][j] + Ai[tt] * sr[tt][j] + Br[tt] * wi + bi[tt] * wr;
            sr[tt][j] = nr; si[tt][j] = ni;
        }
}
template <int BJ>
__device__ __forceinline__ void gate_reg_h2(h2 (&sr)[2][8], h2 (&si)[2][8],
                                            const h2* arai, const h2* brbi) {
#pragma unroll
    for (int tt = 0; tt < 2; ++tt) {
        const h2 ar = splat_lo(arai[tt]), ai = splat_hi(arai[tt]);
        const h2 br = splat_lo(brbi[tt]), bi = splat_hi(brbi[tt]);
#pragma unroll
        for (int j = 0; j < 8; ++j) if (!(j & BJ)) {
            const int j1 = j | BJ;
            h2 x0r = sr[tt][j], x0i = si[tt][j];
            h2 x1r = sr[tt][j1], x1i = si[tt][j1];
            sr[tt][j]  = ar * x0r - ai * x0i - br * x1r - bi * x1i;
            si[tt][j]  = ar * x0i + ai * x0r - br * x1i + bi * x1r;
            sr[tt][j1] = br * x0r - bi * x0i + ar * x1r + ai * x1i;
            si[tt][j1] = br * x0i + bi * x0r + ar * x1i - ai * x1r;
        }
    }
}
__device__ __forceinline__ void gate_elem_h2(h2 (&sr)[2][8], h2 (&si)[2][8],
                                             const h2* arai, const h2* brbi) {
#pragma unroll
    for (int tt = 0; tt < 2; ++tt) {
        const h2 ar = splat_lo(arai[tt]), bi = splat_hi(brbi[tt]);
        // aiV = (ai, -ai): negate hi half; brV = (-br, br): negate lo half
        const h2 aiV = __builtin_bit_cast(h2,
            __builtin_bit_cast(int, splat_hi(arai[tt])) ^ (int)0x80000000);
        const h2 brV = __builtin_bit_cast(h2,
            __builtin_bit_cast(int, splat_lo(brbi[tt])) ^ 0x00008000);
#pragma unroll
        for (int j = 0; j < 8; ++j) {
            h2 swr = h2swap(sr[tt][j]), swi = h2swap(si[tt][j]);
            h2 nr = ar * sr[tt][j] - aiV * si[tt][j] + brV * swr - bi * swi;
            h2 ni = ar * si[tt][j] + aiV * sr[tt][j] + brV * swi + bi * swr;
            sr[tt][j] = nr; si[tt][j] = ni;
        }
    }
}

// CNOT q=6,7,8 composed register permutation
__device__ __forceinline__ void perm678_h(h2* a) {
    h2 o2 = a[2], o4 = a[4], o7 = a[7];
    a[1] = h2swap(a[1]);
    a[2] = a[3]; a[3] = h2swap(o2);
    a[4] = a[6]; a[6] = a[5]; a[5] = h2swap(o7); a[7] = h2swap(o4);
}

// ring CNOTs q -> q+1 (mod 10), 2 tokens interleaved
__device__ __forceinline__ void cnot_ring2(h2 (&sr)[2][8], h2 (&si)[2][8],
                                           int lane, int apm, int a32) {
#pragma unroll
    for (int j = 0; j < 8; ++j)
#pragma unroll
        for (int tt = 0; tt < 2; ++tt) {
            sr[tt][j] = bpermh(apm, sr[tt][j]);
            si[tt][j] = bpermh(apm, si[tt][j]);
        }
    {
        const bool ctrl = (lane & 1);
#pragma unroll
        for (int tt = 0; tt < 2; ++tt)
#pragma unroll
            for (int j = 0; j < 4; ++j) {
                h2 t0 = sr[tt][j], t1 = sr[tt][j + 4];
                sr[tt][j] = ctrl ? t1 : t0; sr[tt][j + 4] = ctrl ? t0 : t1;
                t0 = si[tt][j]; t1 = si[tt][j + 4];
                si[tt][j] = ctrl ? t1 : t0; si[tt][j + 4] = ctrl ? t0 : t1;
            }
    }
#pragma unroll
    for (int tt = 0; tt < 2; ++tt) {
        perm678_h(sr[tt]);
        perm678_h(si[tt]);
    }
#pragma unroll
    for (int j = 0; j < 8; ++j)
#pragma unroll
        for (int tt = 0; tt < 2; ++tt) {
            h2 w = bpermh(a32, sr[tt][j]); sr[tt][j] = (h2){sr[tt][j].x, w.y};
            w = bpermh(a32, si[tt][j]);    si[tt][j] = (h2){si[tt][j].x, w.y};
        }
}

// layer-0 product-state build (fp32), one token
__device__ __forceinline__ void build_product(h2* sr, h2* si, const v4f* Q0,
                                              const float* Aq, const float* Cq,
                                              int lane) {
    v4f f0 = coef(Q0 + 0, Aq[0], Cq[0]);
    bool b0 = (lane & 32);
    float Lr = b0 ? f0.z : f0.x, Li = b0 ? f0.w : f0.y;
#pragma unroll
    for (int q = 1; q < 6; ++q) {
        v4f f = coef(Q0 + 3 * q, Aq[q], Cq[q]);
        bool b = lane & (1 << (5 - q));
        float fr = b ? f.z : f.x, fi = b ? f.w : f.y;
        float nr = Lr * fr - Li * fi, ni = Lr * fi + Li * fr;
        Lr = nr; Li = ni;
    }
    float Pr[8], Pi[8];
    {   // q6 -> j bit2
        v4f f6 = coef(Q0 + 18, Aq[6], Cq[6]);
        Pr[0] = Lr * f6.x - Li * f6.y; Pi[0] = Lr * f6.y + Li * f6.x;
        Pr[4] = Lr * f6.z - Li * f6.w; Pi[4] = Lr * f6.w + Li * f6.z;
    }
    {   // q7 -> j bit1
        v4f f7 = coef(Q0 + 21, Aq[7], Cq[7]);
#pragma unroll
        for (int jj = 0; jj < 8; jj += 4) {
            float tr1 = Pr[jj] * f7.z - Pi[jj] * f7.w;
            float ti1 = Pr[jj] * f7.w + Pi[jj] * f7.z;
            float tr0 = Pr[jj] * f7.x - Pi[jj] * f7.y;
            float ti0 = Pr[jj] * f7.y + Pi[jj] * f7.x;
            Pr[jj] = tr0; Pi[jj] = ti0; Pr[jj + 2] = tr1; Pi[jj + 2] = ti1;
        }
    }
    {   // q8 -> j bit0
        v4f f8 = coef(Q0 + 24, Aq[8], Cq[8]);
#pragma unroll
        for (int jj = 0; jj < 8; jj += 2) {
            float tr1 = Pr[jj] * f8.z - Pi[jj] * f8.w;
            float ti1 = Pr[jj] * f8.w + Pi[jj] * f8.z;
            float tr0 = Pr[jj] * f8.x - Pi[jj] * f8.y;
            float ti0 = Pr[jj] * f8.y + Pi[jj] * f8.x;
            Pr[jj] = tr0; Pi[jj] = ti0; Pr[jj + 1] = tr1; Pi[jj + 1] = ti1;
        }
    }
    {   // q9 -> element
        v4f f9 = coef(Q0 + 27, Aq[9], Cq[9]);
#pragma unroll
        for (int j = 0; j < 8; ++j) {
            float e0r = Pr[j] * f9.x - Pi[j] * f9.y;
            float e0i = Pr[j] * f9.y + Pi[j] * f9.x;
            float e1r = Pr[j] * f9.z - Pi[j] * f9.w;
            float e1i = Pr[j] * f9.w + Pi[j] * f9.z;
            sr[j] = pk2(e0r, e1r);
            si[j] = pk2(e0i, e1i);
        }
    }
}

// ---- prep kernel: transposed out_W + Q tables (f32 and packed f16) ---------
__global__ __launch_bounds__(512) void prep_kernel(
    const float* __restrict__ weights, const float* __restrict__ out_W,
    float* __restrict__ ws)
{
    const int t = threadIdx.x;   // 512 threads
#pragma unroll
    for (int q = 0; q < NQ; ++q)
        ws[q * DQ + t] = out_W[t * NQ + q];
    if (t < QL * NQ) {
        float w0 = weights[t * 2], w1 = weights[t * 2 + 1];
        float cy = __cosf(0.5f * w0), sy = __sinf(0.5f * w0);
        float cz = __cosf(0.5f * w1), sz = __sinf(0.5f * w1);
        float d = cy - sy, e = cy + sy;
        v4f q0 = (v4f){-cz * sy,  sz * sy,  cz * cy,  sz * cy};
        v4f q1 = (v4f){ cz * e,  -sz * e,  -cz * d,  -sz * d};
        v4f q2 = (v4f){-sz * d,  -cz * d,   sz * e,  -cz * e};
        v4f* Q = (v4f*)(ws + QOFF);
        Q[t * 3 + 0] = q0; Q[t * 3 + 1] = q1; Q[t * 3 + 2] = q2;
        h2* Qh = (h2*)(ws + QHOFF);
        Qh[t * 6 + 0] = pk2(q0.x, q0.y); Qh[t * 6 + 1] = pk2(q0.z, q0.w);
        Qh[t * 6 + 2] = pk2(q1.x, q1.y); Qh[t * 6 + 3] = pk2(q1.z, q1.w);
        Qh[t * 6 + 4] = pk2(q2.x, q2.y); Qh[t * 6 + 5] = pk2(q2.z, q2.w);
    }
}

__global__ __launch_bounds__(256) void quantum_kernel(
    const float* __restrict__ x, const float* __restrict__ in_W,
    const float* __restrict__ in_b, const float* __restrict__ gamma,
    const float* __restrict__ beta, const float* __restrict__ ws,
    const float* __restrict__ out_b, float* __restrict__ out)
{
    const int t = threadIdx.x;
    const int lane = t & 63;
    const int tok0 = (blockIdx.x * 4 + (t >> 6)) * 2;   // 2 tokens per wave
    const v4f* Qg = (const v4f*)(ws + QOFF);    // f32 (layer 0)
    const h2*  Qh = (const h2*)(ws + QHOFF);    // f16 (layers 1..3)

    // hoisted bpermute byte addresses
    const int a32 = (lane ^ 32) << 2;
    const int a16 = (lane ^ 16) << 2;
    const int a4  = (lane ^ 4)  << 2;
    int srcl = lane;
#pragma unroll
    for (int q = 4; q >= 0; --q) {
        const int bc = 5 - q, bt = bc - 1;
        srcl ^= ((srcl >> bc) & 1) << bt;
    }
    const int apm = srcl << 2;

    // ---------------- stage 1: h = tanh(x @ in_W^T + in_b), then LN ----------
    const v4f* xr0 = (const v4f*)(x + (size_t)tok0 * DQ);
    const v4f* xr1 = (const v4f*)(x + (size_t)(tok0 + 1) * DQ);
    const v4f* inW4 = (const v4f*)in_W;
    const v4f xk00 = xr0[lane], xk01 = xr0[lane + 64];
    const v4f xk10 = xr1[lane], xk11 = xr1[lane + 64];
    float h[2][NQ];
#pragma unroll
    for (int q = 0; q < NQ; ++q) {
        v4f w0 = inW4[q * (DQ / 4) + lane];
        v4f w1 = inW4[q * (DQ / 4) + lane + 64];
        v4f a0 = xk00 * w0 + xk01 * w1;
        v4f a1 = xk10 * w0 + xk11 * w1;
        h[0][q] = (a0.x + a0.y) + (a0.z + a0.w);
        h[1][q] = (a1.x + a1.y) + (a1.z + a1.w);
    }
    reduceNf<2 * NQ>(&h[0][0], a32, a16, a4);

    h2 AC[2][NQ];           // (A, C) packed per token/qubit
    h2 sr[2][8], si[2][8];  // statevectors
#pragma unroll
    for (int tt = 0; tt < 2; ++tt) {
        float mu = 0.f;
#pragma unroll
        for (int q = 0; q < NQ; ++q) {
            float e = __expf(2.f * (h[tt][q] + in_b[q]));
            h[tt][q] = (e - 1.f) * __builtin_amdgcn_rcpf(e + 1.f);
            mu += h[tt][q];
        }
        mu *= 0.1f;
        float var = 0.f;
#pragma unroll
        for (int q = 0; q < NQ; ++q) { float d0 = h[tt][q] - mu; var += d0 * d0; }
        var *= 0.1f;
        const float rstd = rsqrtf(var + 1e-5f);

        float Aq[NQ], Cq[NQ];
#pragma unroll
        for (int q = 0; q < NQ; ++q) {
            float f = (h[tt][q] - mu) * rstd * gamma[q] + beta[q];
            float hf = 0.5f * f;
            float c = __cosf(hf), s = __sinf(hf);
            Aq[q] = c * c;
            Cq[q] = c * s;
            AC[tt][q] = pk2(Aq[q], Cq[q]);
        }
        // ---------------- layer 0: product state built directly (fp32) ------
        build_product(sr[tt], si[tt], Qg, Aq, Cq, lane);
    }
    cnot_ring2(sr, si, lane, apm, a32);

    // ---------------- layers 1..3 (final ring absorbed into measurement) -----
    // rolled: keeps I-cache footprint ~1/3 of full unroll
#pragma unroll 1
    for (int l = 1; l < QL; ++l) {
        const h2* Ql = Qh + l * NQ * 6;
        h2 arai[2], brbi[2];
        coefh2(Ql + 0 * 6, AC, 0, arai, brbi); gate_lane_hp2(sr, si, arai, brbi, lane & 32, a32);
        coefh2(Ql + 2 * 6, AC, 2, arai, brbi); gate_lane_hd2<8>(sr, si, arai, brbi, lane & 8);
        coefh2(Ql + 1 * 6, AC, 1, arai, brbi); gate_lane_hp2(sr, si, arai, brbi, lane & 16, a16);
        coefh2(Ql + 4 * 6, AC, 4, arai, brbi); gate_lane_hd2<2>(sr, si, arai, brbi, lane & 2);
        coefh2(Ql + 3 * 6, AC, 3, arai, brbi); gate_lane_hp2(sr, si, arai, brbi, lane & 4, a4);
        coefh2(Ql + 5 * 6, AC, 5, arai, brbi); gate_lane_hd2<1>(sr, si, arai, brbi, lane & 1);
        coefh2(Ql + 6 * 6, AC, 6, arai, brbi); gate_reg_h2<4>(sr, si, arai, brbi);
        coefh2(Ql + 7 * 6, AC, 7, arai, brbi); gate_reg_h2<2>(sr, si, arai, brbi);
        coefh2(Ql + 8 * 6, AC, 8, arai, brbi); gate_reg_h2<1>(sr, si, arai, brbi);
        coefh2(Ql + 9 * 6, AC, 9, arai, brbi); gate_elem_h2(sr, si, arai, brbi);
        if (l < QL - 1) cnot_ring2(sr, si, lane, apm, a32);
    }

    // ---------------- measurement (packed f16, ring-relabeled signs) ---------
    const bool P1 = __popc(lane & 0x30) & 1;
    const bool P2 = __popc(lane & 0x38) & 1;
    const bool P3 = __popc(lane & 0x3C) & 1;
    const bool P4 = __popc(lane & 0x3E) & 1;
    const bool P5 = __popc(lane & 0x3F) & 1;
    const bool PX = __popc(lane & 0x1F) & 1;   // qubit0: P9 ^ Q0
    h2 zp[10];  // [tt*5 + i]
#pragma unroll
    for (int tt = 0; tt < 2; ++tt) {
        h2 aP = (h2){0, 0}, a6 = (h2){0, 0}, a7 = (h2){0, 0}, aT = (h2){0, 0};
#pragma unroll
        for (int j = 0; j < 8; ++j) {
            h2 p = sr[tt][j] * sr[tt][j] + si[tt][j] * si[tt][j];
            aP += p;
            if (j & 4) a6 -= p; else a6 += p;                        // j2
            if (((j >> 2) ^ (j >> 1)) & 1) a7 -= p; else a7 += p;    // j2^j1
            if (((j >> 2) ^ (j >> 1) ^ j) & 1) aT -= p; else aT += p;// j2^j1^j0
        }
        const float A0 = (float)aP.x + (float)aP.y;
        const float B6 = (float)a6.x + (float)a6.y;
        const float B7 = (float)a7.x + (float)a7.y;
        const float B8 = (float)aT.x + (float)aT.y;
        const float B9 = (float)aT.x - (float)aT.y;
        float z[NQ];
        z[0] = PX ? -B9 : B9;
        z[1] = P1 ? -A0 : A0;
        z[2] = P2 ? -A0 : A0;
        z[3] = P3 ? -A0 : A0;
        z[4] = P4 ? -A0 : A0;
        z[5] = P5 ? -A0 : A0;
        z[6] = P5 ? -B6 : B6;
        z[7] = P5 ? -B7 : B7;
        z[8] = P5 ? -B8 : B8;
        z[9] = P5 ? -B9 : B9;
#pragma unroll
        for (int i = 0; i < 5; ++i) zp[tt * 5 + i] = pk2(z[2 * i], z[2 * i + 1]);
    }

    // packed f16 butterfly broadcast-reduce of z (10 h2 regs, 6 steps)
#pragma unroll
    for (int i = 0; i < 10; ++i) {
        zp[i] += bpermh(a32, zp[i]);
        zp[i] += bpermh(a16, zp[i]);
        zp[i] += dppxh<8>(zp[i]);
        zp[i] += bpermh(a4, zp[i]);
        zp[i] += dppxh<2>(zp[i]);
        zp[i] += dppxh<1>(zp[i]);
    }
    float zf[2][NQ];
#pragma unroll
    for (int tt = 0; tt < 2; ++tt)
#pragma unroll
        for (int i = 0; i < 5; ++i) {
            zf[tt][2 * i]     = (float)zp[tt * 5 + i].x;
            zf[tt][2 * i + 1] = (float)zp[tt * 5 + i].y;
        }

    // ---------------- epilogue: out = x + z @ out_W^T + out_b ----------------
    v4f* or0 = (v4f*)(out + (size_t)tok0 * DQ);
    v4f* or1 = (v4f*)(out + (size_t)(tok0 + 1) * DQ);
    const v4f* ob4 = (const v4f*)out_b;
    const v4f* oWt4 = (const v4f*)ws;   // transposed out_W [q][d]
#pragma unroll
    for (int k = 0; k < 2; ++k) {
        const int d4 = lane + 64 * k;
        const v4f b = ob4[d4];
        v4f acc0 = xr0[d4] + b;
        v4f acc1 = xr1[d4] + b;
#pragma unroll
        for (int q = 0; q < NQ; ++q) {
            v4f w = oWt4[q * (DQ / 4) + d4];
            acc0 = zf[0][q] * w + acc0;
            acc1 = zf[1][q] * w + acc1;
        }
        or0[d4] = acc0;
        or1[d4] = acc1;
    }
}

extern "C" void kernel_launch(void* const* d_in, const int* in_sizes, int n_in,
                              void* d_out, int out_size, void* d_ws, size_t ws_size,
                              hipStream_t stream) {
    const float* x       = (const float*)d_in[0];
    const float* in_W    = (const float*)d_in[1];
    const float* in_b    = (const float*)d_in[2];
    const float* gamma   = (const float*)d_in[3];
    const float* beta    = (const float*)d_in[4];
    const float* weights = (const float*)d_in[5];
    const float* out_W   = (const float*)d_in[6];
    const float* out_b   = (const float*)d_in[7];
    float* out = (float*)d_out;
    float* ws = (float*)d_ws;

    hipLaunchKernelGGL(prep_kernel, dim3(1), dim3(512), 0, stream,
                       weights, out_W, ws);
    hipLaunchKernelGGL(quantum_kernel, dim3(NTOK / 8), dim3(256), 0, stream,
                       x, in_W, in_b, gamma, beta, ws, out_b, out);
}

// Round 7
// 191.409 us; speedup vs baseline: 1.3299x; 1.0131x over previous
//
#include <hip/hip_runtime.h>

// QuantumLayer: B=8, L=2048, D=512, NQ=10, 4 layers, DIM=1024.
// R7 = R1/R6 champion structure + packed-f16 stage-1 reduce.
//   Champion config (measured bowl bottom): 2 tokens/wave, bperm/DPP
//   shuffles, separate prep kernel, rolled layer loop, VGPR=64.
//   R7 change: the stage-1 butterfly reduce of 20 f32 dot-product partials
//   (120 shuffles + 120 adds) is packed into 10 h2 registers -> 60 shuffles
//   + 60 pk-adds (+30 cvt), same pattern as the measurement reduce. Saves
//   ~60 VALU + ~30 DS per wave; f16 partials (<0.4 magnitude) add ~1e-3
//   error vs the existing ~0.03 f16-state budget.
//
// Measured landscape (dispatch us): 1tok 158; 2tok 126 (best); permlane 142
// (VALU-pipe saturated); 4tok 140 (VGPR 104 occupancy cliff); LDS-fused prep
// 143 (same cliff); launch_bounds(256,8)+sincosf 185-205 (scratch spill,
// WRITE 32->300MB). Scored = dispatch + ~65us harness constant.
//
// Statevector packed as half2 per token: amplitude index i (10 bits):
//   lane = i>>4 (bits 9..4), reg r = i&15; r = 2*j + e (j = VGPR idx, e = half)
// qubit q at bit 9-q: q0..q5 -> lane bits 5..0; q6 -> j bit2, q7 -> j bit1,
// q8 -> j bit0, q9 -> element(half).
//
// Per layer/qubit RX(f)->phase(f)->RY(w0)->RZ(w1) fuse into one SU(2) gate
// (ar,ai,br,bi) = Q0 + A*Q1 + C*Q2, A=c^2, C=c*s. Q* weight-only, stored in
// d_ws BOTH as f32 (layer-0 product-state build) and packed f16 (layers 1..3
// coef math in v_pk_fma_f16). Final CNOT ring absorbed into measurement signs.
// Layer loop rolled (#pragma unroll 1) to keep I-cache footprint bounded.
#define NQ 10
#define DQ 512
#define QL 4
#define NTOK (8 * 2048)
#define QOFF (NQ * DQ)          // float offset of f32 Q tables inside ws
#define QHOFF (QOFF + 480)      // float offset of f16 Q tables inside ws

typedef float v2f __attribute__((ext_vector_type(2)));
typedef float v4f __attribute__((ext_vector_type(4)));
typedef _Float16 h2 __attribute__((ext_vector_type(2)));

// ---- cross-lane helpers (HW-proven) ----------------------------------------
__device__ __forceinline__ int bperm(int addr, int v) {
    return __builtin_amdgcn_ds_bpermute(addr, v);
}
__device__ __forceinline__ float bpermf(int addr, float v) {
    return __builtin_bit_cast(float, bperm(addr, __builtin_bit_cast(int, v)));
}
__device__ __forceinline__ h2 bpermh(int addr, h2 v) {
    return __builtin_bit_cast(h2, bperm(addr, __builtin_bit_cast(int, v)));
}
template <int CTRL>
__device__ __forceinline__ int dppi(int i) {
    return __builtin_amdgcn_update_dpp(i, i, CTRL, 0xF, 0xF, false);
}
template <int M>   // M in {1,2,8}
__device__ __forceinline__ float dppxf(float v) {
    int i = __builtin_bit_cast(int, v);
    if constexpr (M == 1)      i = dppi<0xB1>(i);   // quad_perm [1,0,3,2]
    else if constexpr (M == 2) i = dppi<0x4E>(i);   // quad_perm [2,3,0,1]
    else                       i = dppi<0x128>(i);  // row_ror:8 == xor 8
    return __builtin_bit_cast(float, i);
}
template <int M>   // M in {1,2,8}
__device__ __forceinline__ h2 dppxh(h2 v) {
    int i = __builtin_bit_cast(int, v);
    if constexpr (M == 1)      i = dppi<0xB1>(i);
    else if constexpr (M == 2) i = dppi<0x4E>(i);
    else                       i = dppi<0x128>(i);
    return __builtin_bit_cast(h2, i);
}

// packed-f16 butterfly broadcast-reduce over 64 lanes, N h2 registers
template <int N>
__device__ __forceinline__ void reduceNh(h2* z, int a32, int a16, int a4) {
#pragma unroll
    for (int i = 0; i < N; ++i) {
        z[i] += bpermh(a32, z[i]);
        z[i] += bpermh(a16, z[i]);
        z[i] += dppxh<8>(z[i]);
        z[i] += bpermh(a4, z[i]);
        z[i] += dppxh<2>(z[i]);
        z[i] += dppxh<1>(z[i]);
    }
}

__device__ __forceinline__ h2 pk2(float a, float b) {
    return __builtin_bit_cast(h2, __builtin_amdgcn_cvt_pkrtz(a, b));
}
__device__ __forceinline__ h2 h2swap(h2 v) {
    return __builtin_shufflevector(v, v, 1, 0);
}
__device__ __forceinline__ h2 splat_lo(h2 v) {
    return __builtin_shufflevector(v, v, 0, 0);
}
__device__ __forceinline__ h2 splat_hi(h2 v) {
    return __builtin_shufflevector(v, v, 1, 1);
}

// f32 coef for layer-0 build: Q0 + A*Q1 + C*Q2
__device__ __forceinline__ v4f coef(const v4f* Q, float A, float C) {
    return Q[0] + A * Q[1] + C * Q[2];
}
// f16 coef for layers 1..3, both tokens: per gate 6 h2 at Qg6 -> (arai, brbi)
__device__ __forceinline__ void coefh2(const h2* Qg6, const h2 AC[2][NQ], int q,
                                       h2* arai, h2* brbi) {
    const h2 q0 = Qg6[0], q1 = Qg6[1], q2 = Qg6[2];
    const h2 q3 = Qg6[3], q4 = Qg6[4], q5 = Qg6[5];
#pragma unroll
    for (int tt = 0; tt < 2; ++tt) {
        h2 A2 = splat_lo(AC[tt][q]), C2 = splat_hi(AC[tt][q]);
        arai[tt] = q0 + A2 * q2 + C2 * q4;
        brbi[tt] = q1 + A2 * q3 + C2 * q5;
    }
}

// ---- SU(2) gate application on f16-packed state, 2 tokens interleaved ------
__device__ __forceinline__ void gate_lane_hp2(h2 (&sr)[2][8], h2 (&si)[2][8],
                                              const h2* arai, const h2* brbi,
                                              bool bit, int addr) {
    h2 ar[2], br[2], bi[2], Ai[2], Br[2];
#pragma unroll
    for (int tt = 0; tt < 2; ++tt) {
        ar[tt] = splat_lo(arai[tt]);
        h2 ai = splat_hi(arai[tt]);
        br[tt] = splat_lo(brbi[tt]);
        bi[tt] = splat_hi(brbi[tt]);
        Ai[tt] = bit ? -ai : ai;
        Br[tt] = bit ? br[tt] : -br[tt];
    }
#pragma unroll
    for (int j = 0; j < 8; ++j)
#pragma unroll
        for (int tt = 0; tt < 2; ++tt) {
            h2 wr = bpermh(addr, sr[tt][j]), wi = bpermh(addr, si[tt][j]);
            h2 nr = ar[tt] * sr[tt][j] - Ai[tt] * si[tt][j] + Br[tt] * wr - bi[tt] * wi;
            h2 ni = ar[tt] * si[tt][j] + Ai[tt] * sr[tt][j] + Br[tt] * wi + bi[tt] * wr;
            sr[tt][j] = nr; si[tt][j] = ni;
        }
}
template <int M>
__device__ __forceinline__ void gate_lane_hd2(h2 (&sr)[2][8], h2 (&si)[2][8],
                                              const h2* arai, const h2* brbi,
                                              bool bit) {
    h2 ar[2], br[2], bi[2], Ai[2], Br[2];
#pragma unroll
    for (int tt = 0; tt < 2; ++tt) {
        ar[tt] = splat_lo(arai[tt]);
        h2 ai = splat_hi(arai[tt]);
        br[tt] = splat_lo(brbi[tt]);
        bi[tt] = splat_hi(brbi[tt]);
        Ai[tt] = bit ? -ai : ai;
        Br[tt] = bit ? br[tt] : -br[tt];
    }
#pragma unroll
    for (int j = 0; j < 8; ++j)
#pragma unroll
        for (int tt = 0; tt < 2; ++tt) {
            h2 wr = dppxh<M>(sr[tt][j]), wi = dppxh<M>(si[tt][j]);
            h2 nr = ar[tt] * sr[tt][j] - Ai[tt] * si[tt][j] + Br[tt] * wr - bi[tt] * wi;
            h2 ni = ar[tt] * si[tt][j] + Ai[tt] * sr[tt][j] + Br[tt] * wi + bi[tt] * wr;
            sr[tt][j] = nr; si[tt][j] = ni;
        }
}
template <int BJ>
__device__ __forceinline__ void gate_reg_h2(h2 (&sr)[2][8], h2 (&si)[2][8],
                                            const h2* arai, const h2* brbi) {
#pragma unroll
    for (int tt = 0; tt < 2; ++tt) {
        const h2 ar = splat_lo(arai[tt]), ai = splat_hi(arai[tt]);
        const h2 br = splat_lo(brbi[tt]), bi = splat_hi(brbi[tt]);
#pragma unroll
        for (int j = 0; j < 8; ++j) if (!(j & BJ)) {
            const int j1 = j | BJ;
            h2 x0r = sr[tt][j], x0i = si[tt][j];
            h2 x1r = sr[tt][j1], x1i = si[tt][j1];
            sr[tt][j]  = ar * x0r - ai * x0i - br * x1r - bi * x1i;
            si[tt][j]  = ar * x0i + ai * x0r - br * x1i + bi * x1r;
            sr[tt][j1] = br * x0r - bi * x0i + ar * x1r + ai * x1i;
            si[tt][j1] = br * x0i + bi * x0r + ar * x1i - ai * x1r;
        }
    }
}
__device__ __forceinline__ void gate_elem_h2(h2 (&sr)[2][8], h2 (&si)[2][8],
                                             const h2* arai, const h2* brbi) {
#pragma unroll
    for (int tt = 0; tt < 2; ++tt) {
        const h2 ar = splat_lo(arai[tt]), bi = splat_hi(brbi[tt]);
        // aiV = (ai, -ai): negate hi half; brV = (-br, br): negate lo half
        const h2 aiV = __builtin_bit_cast(h2,
            __builtin_bit_cast(int, splat_hi(arai[tt])) ^ (int)0x80000000);
        const h2 brV = __builtin_bit_cast(h2,
            __builtin_bit_cast(int, splat_lo(brbi[tt])) ^ 0x00008000);
#pragma unroll
        for (int j = 0; j < 8; ++j) {
            h2 swr = h2swap(sr[tt][j]), swi = h2swap(si[tt][j]);
            h2 nr = ar * sr[tt][j] - aiV * si[tt][j] + brV * swr - bi * swi;
            h2 ni = ar * si[tt][j] + aiV * sr[tt][j] + brV * swi + bi * swr;
            sr[tt][j] = nr; si[tt][j] = ni;
        }
    }
}

// CNOT q=6,7,8 composed register permutation
__device__ __forceinline__ void perm678_h(h2* a) {
    h2 o2 = a[2], o4 = a[4], o7 = a[7];
    a[1] = h2swap(a[1]);
    a[2] = a[3]; a[3] = h2swap(o2);
    a[4] = a[6]; a[6] = a[5]; a[5] = h2swap(o7); a[7] = h2swap(o4);
}

// ring CNOTs q -> q+1 (mod 10), 2 tokens interleaved
__device__ __forceinline__ void cnot_ring2(h2 (&sr)[2][8], h2 (&si)[2][8],
                                           int lane, int apm, int a32) {
#pragma unroll
    for (int j = 0; j < 8; ++j)
#pragma unroll
        for (int tt = 0; tt < 2; ++tt) {
            sr[tt][j] = bpermh(apm, sr[tt][j]);
            si[tt][j] = bpermh(apm, si[tt][j]);
        }
    {
        const bool ctrl = (lane & 1);
#pragma unroll
        for (int tt = 0; tt < 2; ++tt)
#pragma unroll
            for (int j = 0; j < 4; ++j) {
                h2 t0 = sr[tt][j], t1 = sr[tt][j + 4];
                sr[tt][j] = ctrl ? t1 : t0; sr[tt][j + 4] = ctrl ? t0 : t1;
                t0 = si[tt][j]; t1 = si[tt][j + 4];
                si[tt][j] = ctrl ? t1 : t0; si[tt][j + 4] = ctrl ? t0 : t1;
            }
    }
#pragma unroll
    for (int tt = 0; tt < 2; ++tt) {
        perm678_h(sr[tt]);
        perm678_h(si[tt]);
    }
#pragma unroll
    for (int j = 0; j < 8; ++j)
#pragma unroll
        for (int tt = 0; tt < 2; ++tt) {
            h2 w = bpermh(a32, sr[tt][j]); sr[tt][j] = (h2){sr[tt][j].x, w.y};
            w = bpermh(a32, si[tt][j]);    si[tt][j] = (h2){si[tt][j].x, w.y};
        }
}

// layer-0 product-state build (fp32), one token
__device__ __forceinline__ void build_product(h2* sr, h2* si, const v4f* Q0,
                                              const float* Aq, const float* Cq,
                                              int lane) {
    v4f f0 = coef(Q0 + 0, Aq[0], Cq[0]);
    bool b0 = (lane & 32);
    float Lr = b0 ? f0.z : f0.x, Li = b0 ? f0.w : f0.y;
#pragma unroll
    for (int q = 1; q < 6; ++q) {
        v4f f = coef(Q0 + 3 * q, Aq[q], Cq[q]);
        bool b = lane & (1 << (5 - q));
        float fr = b ? f.z : f.x, fi = b ? f.w : f.y;
        float nr = Lr * fr - Li * fi, ni = Lr * fi + Li * fr;
        Lr = nr; Li = ni;
    }
    float Pr[8], Pi[8];
    {   // q6 -> j bit2
        v4f f6 = coef(Q0 + 18, Aq[6], Cq[6]);
        Pr[0] = Lr * f6.x - Li * f6.y; Pi[0] = Lr * f6.y + Li * f6.x;
        Pr[4] = Lr * f6.z - Li * f6.w; Pi[4] = Lr * f6.w + Li * f6.z;
    }
    {   // q7 -> j bit1
        v4f f7 = coef(Q0 + 21, Aq[7], Cq[7]);
#pragma unroll
        for (int jj = 0; jj < 8; jj += 4) {
            float tr1 = Pr[jj] * f7.z - Pi[jj] * f7.w;
            float ti1 = Pr[jj] * f7.w + Pi[jj] * f7.z;
            float tr0 = Pr[jj] * f7.x - Pi[jj] * f7.y;
            float ti0 = Pr[jj] * f7.y + Pi[jj] * f7.x;
            Pr[jj] = tr0; Pi[jj] = ti0; Pr[jj + 2] = tr1; Pi[jj + 2] = ti1;
        }
    }
    {   // q8 -> j bit0
        v4f f8 = coef(Q0 + 24, Aq[8], Cq[8]);
#pragma unroll
        for (int jj = 0; jj < 8; jj += 2) {
            float tr1 = Pr[jj] * f8.z - Pi[jj] * f8.w;
            float ti1 = Pr[jj] * f8.w + Pi[jj] * f8.z;
            float tr0 = Pr[jj] * f8.x - Pi[jj] * f8.y;
            float ti0 = Pr[jj] * f8.y + Pi[jj] * f8.x;
            Pr[jj] = tr0; Pi[jj] = ti0; Pr[jj + 1] = tr1; Pi[jj + 1] = ti1;
        }
    }
    {   // q9 -> element
        v4f f9 = coef(Q0 + 27, Aq[9], Cq[9]);
#pragma unroll
        for (int j = 0; j < 8; ++j) {
            float e0r = Pr[j] * f9.x - Pi[j] * f9.y;
            float e0i = Pr[j] * f9.y + Pi[j] * f9.x;
            float e1r = Pr[j] * f9.z - Pi[j] * f9.w;
            float e1i = Pr[j] * f9.w + Pi[j] * f9.z;
            sr[j] = pk2(e0r, e1r);
            si[j] = pk2(e0i, e1i);
        }
    }
}

// ---- prep kernel: transposed out_W + Q tables (f32 and packed f16) ---------
__global__ __launch_bounds__(512) void prep_kernel(
    const float* __restrict__ weights, const float* __restrict__ out_W,
    float* __restrict__ ws)
{
    const int t = threadIdx.x;   // 512 threads
#pragma unroll
    for (int q = 0; q < NQ; ++q)
        ws[q * DQ + t] = out_W[t * NQ + q];
    if (t < QL * NQ) {
        float w0 = weights[t * 2], w1 = weights[t * 2 + 1];
        float cy = __cosf(0.5f * w0), sy = __sinf(0.5f * w0);
        float cz = __cosf(0.5f * w1), sz = __sinf(0.5f * w1);
        float d = cy - sy, e = cy + sy;
        v4f q0 = (v4f){-cz * sy,  sz * sy,  cz * cy,  sz * cy};
        v4f q1 = (v4f){ cz * e,  -sz * e,  -cz * d,  -sz * d};
        v4f q2 = (v4f){-sz * d,  -cz * d,   sz * e,  -cz * e};
        v4f* Q = (v4f*)(ws + QOFF);
        Q[t * 3 + 0] = q0; Q[t * 3 + 1] = q1; Q[t * 3 + 2] = q2;
        h2* Qh = (h2*)(ws + QHOFF);
        Qh[t * 6 + 0] = pk2(q0.x, q0.y); Qh[t * 6 + 1] = pk2(q0.z, q0.w);
        Qh[t * 6 + 2] = pk2(q1.x, q1.y); Qh[t * 6 + 3] = pk2(q1.z, q1.w);
        Qh[t * 6 + 4] = pk2(q2.x, q2.y); Qh[t * 6 + 5] = pk2(q2.z, q2.w);
    }
}

__global__ __launch_bounds__(256) void quantum_kernel(
    const float* __restrict__ x, const float* __restrict__ in_W,
    const float* __restrict__ in_b, const float* __restrict__ gamma,
    const float* __restrict__ beta, const float* __restrict__ ws,
    const float* __restrict__ out_b, float* __restrict__ out)
{
    const int t = threadIdx.x;
    const int lane = t & 63;
    const int tok0 = (blockIdx.x * 4 + (t >> 6)) * 2;   // 2 tokens per wave
    const v4f* Qg = (const v4f*)(ws + QOFF);    // f32 (layer 0)
    const h2*  Qh = (const h2*)(ws + QHOFF);    // f16 (layers 1..3)

    // hoisted bpermute byte addresses
    const int a32 = (lane ^ 32) << 2;
    const int a16 = (lane ^ 16) << 2;
    const int a4  = (lane ^ 4)  << 2;
    int srcl = lane;
#pragma unroll
    for (int q = 4; q >= 0; --q) {
        const int bc = 5 - q, bt = bc - 1;
        srcl ^= ((srcl >> bc) & 1) << bt;
    }
    const int apm = srcl << 2;

    // ---------------- stage 1: h = tanh(x @ in_W^T + in_b), then LN ----------
    const v4f* xr0 = (const v4f*)(x + (size_t)tok0 * DQ);
    const v4f* xr1 = (const v4f*)(x + (size_t)(tok0 + 1) * DQ);
    const v4f* inW4 = (const v4f*)in_W;
    const v4f xk00 = xr0[lane], xk01 = xr0[lane + 64];
    const v4f xk10 = xr1[lane], xk11 = xr1[lane + 64];
    // per-lane partials packed as (tok0, tok1) h2 per qubit, then one packed
    // butterfly reduce (halves the 20-value f32 reduce: 120->60 shuffles)
    h2 hp[NQ];
#pragma unroll
    for (int q = 0; q < NQ; ++q) {
        v4f w0 = inW4[q * (DQ / 4) + lane];
        v4f w1 = inW4[q * (DQ / 4) + lane + 64];
        v4f a0 = xk00 * w0 + xk01 * w1;
        v4f a1 = xk10 * w0 + xk11 * w1;
        hp[q] = pk2((a0.x + a0.y) + (a0.z + a0.w),
                    (a1.x + a1.y) + (a1.z + a1.w));
    }
    reduceNh<NQ>(hp, a32, a16, a4);
    float h[2][NQ];
#pragma unroll
    for (int q = 0; q < NQ; ++q) {
        h[0][q] = (float)hp[q].x;
        h[1][q] = (float)hp[q].y;
    }

    h2 AC[2][NQ];           // (A, C) packed per token/qubit
    h2 sr[2][8], si[2][8];  // statevectors
#pragma unroll
    for (int tt = 0; tt < 2; ++tt) {
        float mu = 0.f;
#pragma unroll
        for (int q = 0; q < NQ; ++q) {
            float e = __expf(2.f * (h[tt][q] + in_b[q]));
            h[tt][q] = (e - 1.f) * __builtin_amdgcn_rcpf(e + 1.f);
            mu += h[tt][q];
        }
        mu *= 0.1f;
        float var = 0.f;
#pragma unroll
        for (int q = 0; q < NQ; ++q) { float d0 = h[tt][q] - mu; var += d0 * d0; }
        var *= 0.1f;
        const float rstd = rsqrtf(var + 1e-5f);

        float Aq[NQ], Cq[NQ];
#pragma unroll
        for (int q = 0; q < NQ; ++q) {
            float f = (h[tt][q] - mu) * rstd * gamma[q] + beta[q];
            float hf = 0.5f * f;
            float c = __cosf(hf), s = __sinf(hf);
            Aq[q] = c * c;
            Cq[q] = c * s;
            AC[tt][q] = pk2(Aq[q], Cq[q]);
        }
        // ---------------- layer 0: product state built directly (fp32) ------
        build_product(sr[tt], si[tt], Qg, Aq, Cq, lane);
    }
    cnot_ring2(sr, si, lane, apm, a32);

    // ---------------- layers 1..3 (final ring absorbed into measurement) -----
    // rolled: keeps I-cache footprint ~1/3 of full unroll
#pragma unroll 1
    for (int l = 1; l < QL; ++l) {
        const h2* Ql = Qh + l * NQ * 6;
        h2 arai[2], brbi[2];
        coefh2(Ql + 0 * 6, AC, 0, arai, brbi); gate_lane_hp2(sr, si, arai, brbi, lane & 32, a32);
        coefh2(Ql + 2 * 6, AC, 2, arai, brbi); gate_lane_hd2<8>(sr, si, arai, brbi, lane & 8);
        coefh2(Ql + 1 * 6, AC, 1, arai, brbi); gate_lane_hp2(sr, si, arai, brbi, lane & 16, a16);
        coefh2(Ql + 4 * 6, AC, 4, arai, brbi); gate_lane_hd2<2>(sr, si, arai, brbi, lane & 2);
        coefh2(Ql + 3 * 6, AC, 3, arai, brbi); gate_lane_hp2(sr, si, arai, brbi, lane & 4, a4);
        coefh2(Ql + 5 * 6, AC, 5, arai, brbi); gate_lane_hd2<1>(sr, si, arai, brbi, lane & 1);
        coefh2(Ql + 6 * 6, AC, 6, arai, brbi); gate_reg_h2<4>(sr, si, arai, brbi);
        coefh2(Ql + 7 * 6, AC, 7, arai, brbi); gate_reg_h2<2>(sr, si, arai, brbi);
        coefh2(Ql + 8 * 6, AC, 8, arai, brbi); gate_reg_h2<1>(sr, si, arai, brbi);
        coefh2(Ql + 9 * 6, AC, 9, arai, brbi); gate_elem_h2(sr, si, arai, brbi);
        if (l < QL - 1) cnot_ring2(sr, si, lane, apm, a32);
    }

    // ---------------- measurement (packed f16, ring-relabeled signs) ---------
    const bool P1 = __popc(lane & 0x30) & 1;
    const bool P2 = __popc(lane & 0x38) & 1;
    const bool P3 = __popc(lane & 0x3C) & 1;
    const bool P4 = __popc(lane & 0x3E) & 1;
    const bool P5 = __popc(lane & 0x3F) & 1;
    const bool PX = __popc(lane & 0x1F) & 1;   // qubit0: P9 ^ Q0
    h2 zp[10];  // [tt*5 + i]
#pragma unroll
    for (int tt = 0; tt < 2; ++tt) {
        h2 aP = (h2){0, 0}, a6 = (h2){0, 0}, a7 = (h2){0, 0}, aT = (h2){0, 0};
#pragma unroll
        for (int j = 0; j < 8; ++j) {
            h2 p = sr[tt][j] * sr[tt][j] + si[tt][j] * si[tt][j];
            aP += p;
            if (j & 4) a6 -= p; else a6 += p;                        // j2
            if (((j >> 2) ^ (j >> 1)) & 1) a7 -= p; else a7 += p;    // j2^j1
            if (((j >> 2) ^ (j >> 1) ^ j) & 1) aT -= p; else aT += p;// j2^j1^j0
        }
        const float A0 = (float)aP.x + (float)aP.y;
        const float B6 = (float)a6.x + (float)a6.y;
        const float B7 = (float)a7.x + (float)a7.y;
        const float B8 = (float)aT.x + (float)aT.y;
        const float B9 = (float)aT.x - (float)aT.y;
        float z[NQ];
        z[0] = PX ? -B9 : B9;
        z[1] = P1 ? -A0 : A0;
        z[2] = P2 ? -A0 : A0;
        z[3] = P3 ? -A0 : A0;
        z[4] = P4 ? -A0 : A0;
        z[5] = P5 ? -A0 : A0;
        z[6] = P5 ? -B6 : B6;
        z[7] = P5 ? -B7 : B7;
        z[8] = P5 ? -B8 : B8;
        z[9] = P5 ? -B9 : B9;
#pragma unroll
        for (int i = 0; i < 5; ++i) zp[tt * 5 + i] = pk2(z[2 * i], z[2 * i + 1]);
    }

    // packed f16 butterfly broadcast-reduce of z (10 h2 regs, 6 steps)
    reduceNh<10>(zp, a32, a16, a4);
    float zf[2][NQ];
#pragma unroll
    for (int tt = 0; tt < 2; ++tt)
#pragma unroll
        for (int i = 0; i < 5; ++i) {
            zf[tt][2 * i]     = (float)zp[tt * 5 + i].x;
            zf[tt][2 * i + 1] = (float)zp[tt * 5 + i].y;
        }

    // ---------------- epilogue: out = x + z @ out_W^T + out_b ----------------
    v4f* or0 = (v4f*)(out + (size_t)tok0 * DQ);
    v4f* or1 = (v4f*)(out + (size_t)(tok0 + 1) * DQ);
    const v4f* ob4 = (const v4f*)out_b;
    const v4f* oWt4 = (const v4f*)ws;   // transposed out_W [q][d]
#pragma unroll
    for (int k = 0; k < 2; ++k) {
        const int d4 = lane + 64 * k;
        const v4f b = ob4[d4];
        v4f acc0 = xr0[d4] + b;
        v4f acc1 = xr1[d4] + b;
#pragma unroll
        for (int q = 0; q < NQ; ++q) {
            v4f w = oWt4[q * (DQ / 4) + d4];
            acc0 = zf[0][q] * w + acc0;
            acc1 = zf[1][q] * w + acc1;
        }
        or0[d4] = acc0;
        or1[d4] = acc1;
    }
}

extern "C" void kernel_launch(void* const* d_in, const int* in_sizes, int n_in,
                              void* d_out, int out_size, void* d_ws, size_t ws_size,
                              hipStream_t stream) {
    const float* x       = (const float*)d_in[0];
    const float* in_W    = (const float*)d_in[1];
    const float* in_b    = (const float*)d_in[2];
    const float* gamma   = (const float*)d_in[3];
    const float* beta    = (const float*)d_in[4];
    const float* weights = (const float*)d_in[5];
    const float* out_W   = (const float*)d_in[6];
    const float* out_b   = (const float*)d_in[7];
    float* out = (float*)d_out;
    float* ws = (float*)d_ws;

    hipLaunchKernelGGL(prep_kernel, dim3(1), dim3(512), 0, stream,
                       weights, out_W, ws);
    hipLaunchKernelGGL(quantum_kernel, dim3(NTOK / 8), dim3(256), 0, stream,
                       x, in_W, in_b, gamma, beta, ws, out_b, out);
}